// Round 1
// baseline (435.396 us; speedup 1.0000x reference)
//
#include <hip/hip_runtime.h>

#define B_  4
#define S_  1024
#define E_  256
#define H_  32
#define DK_ 8
#define NQ_ 8
#define FF_ 1024
#define M_  (B_*S_)   // 4096 tokens

// ---------------- elementwise: q_out = cos(x + theta_attn[e%8]) ----------------
__global__ __launch_bounds__(256) void qout_kernel(const float* __restrict__ x,
                                                   const float* __restrict__ theta,
                                                   float* __restrict__ qout, int n) {
    int i = blockIdx.x * 256 + threadIdx.x;
    if (i < n) qout[i] = cosf(x[i] + theta[i & 7]);
}

// ---------------- w_eff = w_comb @ w_out  (E x E), b_eff = w_comb@b_out + b_comb ----------------
__global__ __launch_bounds__(256) void weff_kernel(const float* __restrict__ w_comb,
                                                   const float* __restrict__ w_out,
                                                   float* __restrict__ weff) {
    int i = blockIdx.x, j = threadIdx.x;
    float s = 0.f;
    for (int k = 0; k < E_; ++k) s += w_comb[i * E_ + k] * w_out[k * E_ + j];
    weff[i * E_ + j] = s;
}

__global__ __launch_bounds__(256) void beff_kernel(const float* __restrict__ w_comb,
                                                   const float* __restrict__ b_out,
                                                   const float* __restrict__ b_comb,
                                                   float* __restrict__ beff) {
    int i = threadIdx.x;
    float s = b_comb[i];
    for (int k = 0; k < E_; ++k) s += w_comb[i * E_ + k] * b_out[k];
    beff[i] = s;
}

// ---------------- generic C[M,N] = A[M,K] @ W[N,K]^T + bias[N] ----------------
// 64x64 tile, 256 threads, 4x4 register tile, K-tile 16.
__global__ __launch_bounds__(256) void gemm_kernel(const float* __restrict__ A,
                                                   const float* __restrict__ W,
                                                   const float* __restrict__ bias,
                                                   float* __restrict__ C,
                                                   int Mdim, int Ndim, int Kdim) {
    __shared__ float As[16][65];
    __shared__ float Ws[16][65];
    int bm = blockIdx.y * 64, bn = blockIdx.x * 64;
    int tid = threadIdx.x;
    int tr = tid >> 4, tc = tid & 15;
    float acc[4][4] = {};
    for (int k0 = 0; k0 < Kdim; k0 += 16) {
#pragma unroll
        for (int i = 0; i < 4; ++i) {
            int idx = tid + i * 256;
            int r = idx >> 4, c = idx & 15;
            As[c][r] = A[(size_t)(bm + r) * Kdim + k0 + c];
            Ws[c][r] = W[(size_t)(bn + r) * Kdim + k0 + c];
        }
        __syncthreads();
#pragma unroll
        for (int kk = 0; kk < 16; ++kk) {
            float a[4], w[4];
#pragma unroll
            for (int i = 0; i < 4; ++i) a[i] = As[kk][tr * 4 + i];
#pragma unroll
            for (int j = 0; j < 4; ++j) w[j] = Ws[kk][tc * 4 + j];
#pragma unroll
            for (int i = 0; i < 4; ++i)
#pragma unroll
                for (int j = 0; j < 4; ++j) acc[i][j] += a[i] * w[j];
        }
        __syncthreads();
    }
#pragma unroll
    for (int i = 0; i < 4; ++i) {
        int mrow = bm + tr * 4 + i;
        int ncol = bn + tc * 4;
        float4 o = make_float4(acc[i][0] + bias[ncol + 0],
                               acc[i][1] + bias[ncol + 1],
                               acc[i][2] + bias[ncol + 2],
                               acc[i][3] + bias[ncol + 3]);
        *(float4*)(C + (size_t)mrow * Ndim + ncol) = o;
    }
}

// ---------------- attention: one block per (qtile, head, batch) ----------------
// qkv layout: [B*S, 768]; q at +0, k at +256, v at +512, head h dims h*8..h*8+7
__global__ __launch_bounds__(256) void attn_kernel(const float* __restrict__ qkv,
                                                   float* __restrict__ ctx) {
    __shared__ float ks[S_][DK_];
    __shared__ float vs[S_][DK_];
    int qt = blockIdx.x, h = blockIdx.y, b = blockIdx.z;
    const float* base = qkv + (size_t)b * S_ * (3 * E_);
    for (int tok = threadIdx.x; tok < S_; tok += 256) {
        const float* kp = base + (size_t)tok * (3 * E_) + E_ + h * DK_;
        const float* vp = base + (size_t)tok * (3 * E_) + 2 * E_ + h * DK_;
        *(float4*)&ks[tok][0] = *(const float4*)kp;
        *(float4*)&ks[tok][4] = *(const float4*)(kp + 4);
        *(float4*)&vs[tok][0] = *(const float4*)vp;
        *(float4*)&vs[tok][4] = *(const float4*)(vp + 4);
    }
    __syncthreads();
    int row = qt * 256 + threadIdx.x;
    const float* qp = base + (size_t)row * (3 * E_) + h * DK_;
    float4 q0 = *(const float4*)qp, q1 = *(const float4*)(qp + 4);
    float q[8] = {q0.x, q0.y, q0.z, q0.w, q1.x, q1.y, q1.z, q1.w};
    const float scale = 0.35355339059327373f; // 1/sqrt(8)
    float m = -1e30f, l = 0.f, acc[8] = {};
    for (int kk = 0; kk < S_; ++kk) {
        float s = q[0] * ks[kk][0];
#pragma unroll
        for (int d = 1; d < 8; ++d) s += q[d] * ks[kk][d];
        s *= scale;
        float mn = fmaxf(m, s);
        float c = __expf(m - mn);
        float p = __expf(s - mn);
        l = l * c + p;
#pragma unroll
        for (int d = 0; d < 8; ++d) acc[d] = acc[d] * c + p * vs[kk][d];
        m = mn;
    }
    float inv = 1.f / l;
    float* cp = ctx + ((size_t)(b * S_ + row)) * E_ + h * DK_;
    float4 o0 = make_float4(acc[0] * inv, acc[1] * inv, acc[2] * inv, acc[3] * inv);
    float4 o1 = make_float4(acc[4] * inv, acc[5] * inv, acc[6] * inv, acc[7] * inv);
    *(float4*)cp = o0;
    *(float4*)(cp + 4) = o1;
}

// ---------------- residual + layernorm: out = LN(a + r) * g + be ----------------
// one wave (64 lanes) per token, 4 elems per lane
__global__ __launch_bounds__(256) void resid_ln_kernel(const float* __restrict__ a,
                                                       const float* __restrict__ r,
                                                       const float* __restrict__ g,
                                                       const float* __restrict__ be,
                                                       float* __restrict__ out) {
    int wave = threadIdx.x >> 6, lane = threadIdx.x & 63;
    int token = blockIdx.x * 4 + wave;
    const float4 av = ((const float4*)(a + (size_t)token * E_))[lane];
    const float4 rv = ((const float4*)(r + (size_t)token * E_))[lane];
    float v0 = av.x + rv.x, v1 = av.y + rv.y, v2 = av.z + rv.z, v3 = av.w + rv.w;
    float sum = v0 + v1 + v2 + v3;
#pragma unroll
    for (int o = 32; o > 0; o >>= 1) sum += __shfl_xor(sum, o);
    float mu = sum * (1.f / E_);
    float d0 = v0 - mu, d1 = v1 - mu, d2 = v2 - mu, d3 = v3 - mu;
    float ss = d0 * d0 + d1 * d1 + d2 * d2 + d3 * d3;
#pragma unroll
    for (int o = 32; o > 0; o >>= 1) ss += __shfl_xor(ss, o);
    float rstd = rsqrtf(ss * (1.f / E_) + 1e-5f);
    float4 gv = ((const float4*)g)[lane];
    float4 bv = ((const float4*)be)[lane];
    float4 ov = make_float4(d0 * rstd * gv.x + bv.x, d1 * rstd * gv.y + bv.y,
                            d2 * rstd * gv.z + bv.z, d3 * rstd * gv.w + bv.w);
    ((float4*)(out + (size_t)token * E_))[lane] = ov;
}

// ---------------- proj = h @ w_ip^T + b_ip ; qf = cos(theta)*cos(proj) ----------------
__global__ __launch_bounds__(256) void projqf_kernel(const float* __restrict__ h,
                                                     const float* __restrict__ w_ip,
                                                     const float* __restrict__ b_ip,
                                                     const float* __restrict__ theta,
                                                     float* __restrict__ qf) {
    int wave = threadIdx.x >> 6, lane = threadIdx.x & 63;
    int token = blockIdx.x * 4 + wave;
    float4 hv = ((const float4*)(h + (size_t)token * E_))[lane];
    float acc[8];
#pragma unroll
    for (int w = 0; w < 8; ++w) {
        float4 wv = ((const float4*)(w_ip + w * E_))[lane];
        acc[w] = hv.x * wv.x + hv.y * wv.y + hv.z * wv.z + hv.w * wv.w;
    }
#pragma unroll
    for (int o = 32; o > 0; o >>= 1) {
#pragma unroll
        for (int w = 0; w < 8; ++w) acc[w] += __shfl_xor(acc[w], o);
    }
    if (lane == 0) {
#pragma unroll
        for (int w = 0; w < 8; ++w)
            qf[(size_t)token * NQ_ + w] = cosf(theta[w]) * cosf(acc[w] + b_ip[w]);
    }
}

// ---------------- t = relu(qf @ w1^T + b1)  [M, FF] ----------------
__global__ __launch_bounds__(256) void ffn_t_kernel(const float* __restrict__ qf,
                                                    const float* __restrict__ w1,
                                                    const float* __restrict__ b1,
                                                    float* __restrict__ t) {
    int idx = blockIdx.x * 256 + threadIdx.x;   // token*FF + f
    int token = idx >> 10;
    int f = idx & (FF_ - 1);
    const float* qp = qf + (size_t)token * NQ_;
    const float* wp = w1 + (size_t)f * NQ_;
    float s = b1[f];
#pragma unroll
    for (int d = 0; d < 8; ++d) s += qp[d] * wp[d];
    t[idx] = fmaxf(s, 0.f);
}

extern "C" void kernel_launch(void* const* d_in, const int* in_sizes, int n_in,
                              void* d_out, int out_size, void* d_ws, size_t ws_size,
                              hipStream_t stream) {
    const float* x          = (const float*)d_in[0];
    const float* theta_attn = (const float*)d_in[1];
    const float* w_in       = (const float*)d_in[2];
    const float* b_in       = (const float*)d_in[3];
    const float* w_out      = (const float*)d_in[4];
    const float* b_out      = (const float*)d_in[5];
    const float* w_comb     = (const float*)d_in[6];
    const float* b_comb     = (const float*)d_in[7];
    const float* g1         = (const float*)d_in[8];
    const float* be1        = (const float*)d_in[9];
    const float* g2         = (const float*)d_in[10];
    const float* be2        = (const float*)d_in[11];
    const float* w_ip       = (const float*)d_in[12];
    const float* b_ip       = (const float*)d_in[13];
    const float* theta_ffn  = (const float*)d_in[14];
    const float* w1         = (const float*)d_in[15];
    const float* b1         = (const float*)d_in[16];
    const float* w2         = (const float*)d_in[17];
    const float* b2         = (const float*)d_in[18];
    float* out = (float*)d_out;

    float* ws = (float*)d_ws;
    float* qout    = ws + 0;           // 1,048,576 floats
    float* qkv     = ws + 1048576;     // 3,145,728 floats
    float* ctx     = ws + 4194304;     // 1,048,576 floats
    float* h       = ws + 5242880;     // 1,048,576 floats
    float* weff    = ws + 6291456;     // 65,536 floats
    float* beff    = ws + 6356992;     // 256 floats
    float* qf      = ws + 6357248;     // 32,768 floats
    float* attn_out = qout;            // reuse (qout dead after qkv GEMM)
    float* t        = qkv;             // reuse qkv+ctx region (dead after attn/out-proj)
    float* ffn_out  = qout;            // reuse (attn_out dead after LN1)

    // 1) quantum encoding
    qout_kernel<<<(M_ * E_) / 256, 256, 0, stream>>>(x, theta_attn, qout, M_ * E_);
    // 2) fold out-proj + combine into one weight
    weff_kernel<<<E_, E_, 0, stream>>>(w_comb, w_out, weff);
    beff_kernel<<<1, E_, 0, stream>>>(w_comb, b_out, b_comb, beff);
    // 3) qkv = qout @ w_in^T + b_in   [4096, 768]
    gemm_kernel<<<dim3(768 / 64, M_ / 64), 256, 0, stream>>>(qout, w_in, b_in, qkv, M_, 3 * E_, E_);
    // 4) attention -> ctx [4096, 256]
    attn_kernel<<<dim3(S_ / 256, H_, B_), 256, 0, stream>>>(qkv, ctx);
    // 5) attn_out = ctx @ weff^T + beff
    gemm_kernel<<<dim3(E_ / 64, M_ / 64), 256, 0, stream>>>(ctx, weff, beff, attn_out, M_, E_, E_);
    // 6) h = LN(x + attn_out)
    resid_ln_kernel<<<M_ / 4, 256, 0, stream>>>(x, attn_out, g1, be1, h);
    // 7) qf = cos(theta_ffn)*cos(h @ w_ip^T + b_ip)
    projqf_kernel<<<M_ / 4, 256, 0, stream>>>(h, w_ip, b_ip, theta_ffn, qf);
    // 8) t = relu(qf @ w1^T + b1)   [4096, 1024]
    ffn_t_kernel<<<(M_ * FF_) / 256, 256, 0, stream>>>(qf, w1, b1, t);
    // 9) ffn_out = t @ w2^T + b2    [4096, 256]
    gemm_kernel<<<dim3(E_ / 64, M_ / 64), 256, 0, stream>>>(t, w2, b2, ffn_out, M_, E_, FF_);
    // 10) out = LN(h + ffn_out)
    resid_ln_kernel<<<M_ / 4, 256, 0, stream>>>(h, ffn_out, g2, be2, out);
}

// Round 2
// 369.637 us; speedup vs baseline: 1.1779x; 1.1779x over previous
//
#include <hip/hip_runtime.h>

#define B_  4
#define S_  1024
#define E_  256
#define H_  32
#define DK_ 8
#define NQ_ 8
#define FF_ 1024
#define M_  (B_*S_)   // 4096 tokens

typedef __attribute__((ext_vector_type(8))) short bf16x8;
typedef __attribute__((ext_vector_type(4))) short short4v;
typedef __attribute__((ext_vector_type(4))) float f32x4;

__device__ inline short f2bf(float f) {
    union { float f; unsigned u; } v; v.f = f;
    unsigned r = (v.u + 0x7fff + ((v.u >> 16) & 1)) >> 16;   // RNE
    return (short)r;
}

// ---------------- elementwise: q_out = cos(x + theta_attn[e%8]) ----------------
__global__ __launch_bounds__(256) void qout_kernel(const float* __restrict__ x,
                                                   const float* __restrict__ theta,
                                                   float* __restrict__ qout, int n) {
    int i = blockIdx.x * 256 + threadIdx.x;
    if (i < n) qout[i] = cosf(x[i] + theta[i & 7]);
}

// ---------------- w_eff = w_comb @ w_out  (E x E), b_eff = w_comb@b_out + b_comb ----------------
__global__ __launch_bounds__(256) void weff_kernel(const float* __restrict__ w_comb,
                                                   const float* __restrict__ w_out,
                                                   float* __restrict__ weff) {
    int i = blockIdx.x, j = threadIdx.x;
    float s = 0.f;
    for (int k = 0; k < E_; ++k) s += w_comb[i * E_ + k] * w_out[k * E_ + j];
    weff[i * E_ + j] = s;
}

__global__ __launch_bounds__(256) void beff_kernel(const float* __restrict__ w_comb,
                                                   const float* __restrict__ b_out,
                                                   const float* __restrict__ b_comb,
                                                   float* __restrict__ beff) {
    int i = threadIdx.x;
    float s = b_comb[i];
    for (int k = 0; k < E_; ++k) s += w_comb[i * E_ + k] * b_out[k];
    beff[i] = s;
}

// ---------------- generic C[M,N] = A[M,K] @ W[N,K]^T + bias[N] (fp32) ----------------
__global__ __launch_bounds__(256) void gemm_kernel(const float* __restrict__ A,
                                                   const float* __restrict__ W,
                                                   const float* __restrict__ bias,
                                                   float* __restrict__ C,
                                                   int Mdim, int Ndim, int Kdim) {
    __shared__ float As[16][65];
    __shared__ float Ws[16][65];
    int bm = blockIdx.y * 64, bn = blockIdx.x * 64;
    int tid = threadIdx.x;
    int tr = tid >> 4, tc = tid & 15;
    float acc[4][4] = {};
    for (int k0 = 0; k0 < Kdim; k0 += 16) {
#pragma unroll
        for (int i = 0; i < 4; ++i) {
            int idx = tid + i * 256;
            int r = idx >> 4, c = idx & 15;
            As[c][r] = A[(size_t)(bm + r) * Kdim + k0 + c];
            Ws[c][r] = W[(size_t)(bn + r) * Kdim + k0 + c];
        }
        __syncthreads();
#pragma unroll
        for (int kk = 0; kk < 16; ++kk) {
            float a[4], w[4];
#pragma unroll
            for (int i = 0; i < 4; ++i) a[i] = As[kk][tr * 4 + i];
#pragma unroll
            for (int j = 0; j < 4; ++j) w[j] = Ws[kk][tc * 4 + j];
#pragma unroll
            for (int i = 0; i < 4; ++i)
#pragma unroll
                for (int j = 0; j < 4; ++j) acc[i][j] += a[i] * w[j];
        }
        __syncthreads();
    }
#pragma unroll
    for (int i = 0; i < 4; ++i) {
        int mrow = bm + tr * 4 + i;
        int ncol = bn + tc * 4;
        float4 o = make_float4(acc[i][0] + bias[ncol + 0],
                               acc[i][1] + bias[ncol + 1],
                               acc[i][2] + bias[ncol + 2],
                               acc[i][3] + bias[ncol + 3]);
        *(float4*)(C + (size_t)mrow * Ndim + ncol) = o;
    }
}

// ---------------- MFMA flash attention ----------------
// block = (qt: 128 queries, h, b), 256 threads = 4 waves, wave = 32 queries (2 Q-frags)
// scoresT = mfma(A=K16, B=Q16) -> lane: q=l&15, keys (l>>4)*4+r; PV: ctxT = mfma(A=V^T, B=P)
__global__ __launch_bounds__(256) void attn_mfma_kernel(const float* __restrict__ qkv,
                                                        float* __restrict__ ctx) {
    __shared__ short smem[25664];                 // 51328 B
    const int KOFF = 0;                           // K  [1024][8] bf16
    const int VTOFF = 8192;                       // V^T [8][1032] bf16 (padded stride)
    const int POFF = 16448;                       // P   [4w][2qf][16][72] bf16
    int qt = blockIdx.x, h = blockIdx.y, b = blockIdx.z;
    int tid = threadIdx.x;
    const float* base = qkv + (size_t)b * S_ * (3 * E_);

    for (int i = tid; i < 8192; i += 256) {
        int key = i >> 3, d = i & 7;
        const float* rp = base + (size_t)key * (3 * E_) + h * 8 + d;
        smem[KOFF + key * 8 + d] = f2bf(rp[E_]);          // K
        smem[VTOFF + d * 1032 + key] = f2bf(rp[2 * E_]);  // V^T
    }
    __syncthreads();

    int w = tid >> 6, l = tid & 63;
    int lq = l & 15, g = l >> 4;
    const float qscale = 0.5100880289202462f;  // log2(e)/sqrt(8)

    bf16x8 qfrag[2];
#pragma unroll
    for (int qf = 0; qf < 2; ++qf) {
        bf16x8 qv = {};
        if (g == 0) {
            const float* qp = base + (size_t)(qt * 128 + w * 32 + qf * 16 + lq) * (3 * E_) + h * 8;
#pragma unroll
            for (int j = 0; j < 8; ++j) qv[j] = f2bf(qp[j] * qscale);
        }
        qfrag[qf] = qv;
    }

    f32x4 ctxa[2] = {{0.f,0.f,0.f,0.f},{0.f,0.f,0.f,0.f}};
    float mrun[2] = {-1e30f, -1e30f};
    float lrun[2] = {0.f, 0.f};
    short* Pbase0 = &smem[POFF + (w * 2 + 0) * 1152];
    short* Pbase1 = &smem[POFF + (w * 2 + 1) * 1152];

    for (int kt = 0; kt < 16; ++kt) {
        bf16x8 kfrag[4];
#pragma unroll
        for (int kf = 0; kf < 4; ++kf) {
            bf16x8 kv = {};
            if (g == 0) kv = *(bf16x8*)&smem[KOFF + (kt * 64 + kf * 16 + lq) * 8];
            kfrag[kf] = kv;
        }
        f32x4 st[2][4];
#pragma unroll
        for (int qf = 0; qf < 2; ++qf)
#pragma unroll
            for (int kf = 0; kf < 4; ++kf) {
                f32x4 z = {0.f, 0.f, 0.f, 0.f};
                st[qf][kf] = __builtin_amdgcn_mfma_f32_16x16x32_bf16(kfrag[kf], qfrag[qf], z, 0, 0, 0);
            }
#pragma unroll
        for (int qf = 0; qf < 2; ++qf) {
            float mt = st[qf][0][0];
#pragma unroll
            for (int kf = 0; kf < 4; ++kf)
#pragma unroll
                for (int r = 0; r < 4; ++r) mt = fmaxf(mt, st[qf][kf][r]);
            mt = fmaxf(mt, __shfl_xor(mt, 16));
            mt = fmaxf(mt, __shfl_xor(mt, 32));
            float mn = fmaxf(mrun[qf], mt);
            float c = exp2f(mrun[qf] - mn);
            mrun[qf] = mn;
            float ts = 0.f;
#pragma unroll
            for (int kf = 0; kf < 4; ++kf)
#pragma unroll
                for (int r = 0; r < 4; ++r) {
                    float p = exp2f(st[qf][kf][r] - mn);
                    st[qf][kf][r] = p;
                    ts += p;
                }
            ts += __shfl_xor(ts, 16);
            ts += __shfl_xor(ts, 32);
            lrun[qf] = lrun[qf] * c + ts;
#pragma unroll
            for (int r = 0; r < 4; ++r) ctxa[qf][r] *= c;
            short* Pb = (qf == 0) ? Pbase0 : Pbase1;
#pragma unroll
            for (int kf = 0; kf < 4; ++kf) {
                short4v pv;
#pragma unroll
                for (int r = 0; r < 4; ++r) pv[r] = f2bf(st[qf][kf][r]);
                *(short4v*)&Pb[lq * 72 + kf * 16 + g * 4] = pv;
            }
        }
        asm volatile("s_waitcnt lgkmcnt(0)" ::: "memory");
#pragma unroll
        for (int half = 0; half < 2; ++half) {
            bf16x8 vt = *(bf16x8*)&smem[VTOFF + lq * 1032 + kt * 64 + half * 32 + g * 8];
#pragma unroll
            for (int qf = 0; qf < 2; ++qf) {
                short* Pb = (qf == 0) ? Pbase0 : Pbase1;
                bf16x8 pf = *(bf16x8*)&Pb[lq * 72 + half * 32 + g * 8];
                ctxa[qf] = __builtin_amdgcn_mfma_f32_16x16x32_bf16(vt, pf, ctxa[qf], 0, 0, 0);
            }
        }
    }

#pragma unroll
    for (int qf = 0; qf < 2; ++qf) {
        if (g < 2) {
            float inv = 1.f / lrun[qf];
            int token = b * S_ + qt * 128 + w * 32 + qf * 16 + lq;
            float* cp = ctx + (size_t)token * E_ + h * 8 + g * 4;
            *(float4*)cp = make_float4(ctxa[qf][0] * inv, ctxa[qf][1] * inv,
                                       ctxa[qf][2] * inv, ctxa[qf][3] * inv);
        }
    }
}

// ---------------- residual + layernorm ----------------
__global__ __launch_bounds__(256) void resid_ln_kernel(const float* __restrict__ a,
                                                       const float* __restrict__ r,
                                                       const float* __restrict__ g,
                                                       const float* __restrict__ be,
                                                       float* __restrict__ out) {
    int wave = threadIdx.x >> 6, lane = threadIdx.x & 63;
    int token = blockIdx.x * 4 + wave;
    const float4 av = ((const float4*)(a + (size_t)token * E_))[lane];
    const float4 rv = ((const float4*)(r + (size_t)token * E_))[lane];
    float v0 = av.x + rv.x, v1 = av.y + rv.y, v2 = av.z + rv.z, v3 = av.w + rv.w;
    float sum = v0 + v1 + v2 + v3;
#pragma unroll
    for (int o = 32; o > 0; o >>= 1) sum += __shfl_xor(sum, o);
    float mu = sum * (1.f / E_);
    float d0 = v0 - mu, d1 = v1 - mu, d2 = v2 - mu, d3 = v3 - mu;
    float ss = d0 * d0 + d1 * d1 + d2 * d2 + d3 * d3;
#pragma unroll
    for (int o = 32; o > 0; o >>= 1) ss += __shfl_xor(ss, o);
    float rstd = rsqrtf(ss * (1.f / E_) + 1e-5f);
    float4 gv = ((const float4*)g)[lane];
    float4 bv = ((const float4*)be)[lane];
    float4 ov = make_float4(d0 * rstd * gv.x + bv.x, d1 * rstd * gv.y + bv.y,
                            d2 * rstd * gv.z + bv.z, d3 * rstd * gv.w + bv.w);
    ((float4*)(out + (size_t)token * E_))[lane] = ov;
}

// ---------------- proj + quantum ffn encoding ----------------
__global__ __launch_bounds__(256) void projqf_kernel(const float* __restrict__ h,
                                                     const float* __restrict__ w_ip,
                                                     const float* __restrict__ b_ip,
                                                     const float* __restrict__ theta,
                                                     float* __restrict__ qf) {
    int wave = threadIdx.x >> 6, lane = threadIdx.x & 63;
    int token = blockIdx.x * 4 + wave;
    float4 hv = ((const float4*)(h + (size_t)token * E_))[lane];
    float acc[8];
#pragma unroll
    for (int w = 0; w < 8; ++w) {
        float4 wv = ((const float4*)(w_ip + w * E_))[lane];
        acc[w] = hv.x * wv.x + hv.y * wv.y + hv.z * wv.z + hv.w * wv.w;
    }
#pragma unroll
    for (int o = 32; o > 0; o >>= 1) {
#pragma unroll
        for (int w = 0; w < 8; ++w) acc[w] += __shfl_xor(acc[w], o);
    }
    if (lane == 0) {
#pragma unroll
        for (int w = 0; w < 8; ++w)
            qf[(size_t)token * NQ_ + w] = cosf(theta[w]) * cosf(acc[w] + b_ip[w]);
    }
}

// ---------------- t = relu(qf @ w1^T + b1)  [M, FF] ----------------
__global__ __launch_bounds__(256) void ffn_t_kernel(const float* __restrict__ qf,
                                                    const float* __restrict__ w1,
                                                    const float* __restrict__ b1,
                                                    float* __restrict__ t) {
    int idx = blockIdx.x * 256 + threadIdx.x;
    int token = idx >> 10;
    int f = idx & (FF_ - 1);
    const float* qp = qf + (size_t)token * NQ_;
    const float* wp = w1 + (size_t)f * NQ_;
    float s = b1[f];
#pragma unroll
    for (int d = 0; d < 8; ++d) s += qp[d] * wp[d];
    t[idx] = fmaxf(s, 0.f);
}

extern "C" void kernel_launch(void* const* d_in, const int* in_sizes, int n_in,
                              void* d_out, int out_size, void* d_ws, size_t ws_size,
                              hipStream_t stream) {
    const float* x          = (const float*)d_in[0];
    const float* theta_attn = (const float*)d_in[1];
    const float* w_in       = (const float*)d_in[2];
    const float* b_in       = (const float*)d_in[3];
    const float* w_out      = (const float*)d_in[4];
    const float* b_out      = (const float*)d_in[5];
    const float* w_comb     = (const float*)d_in[6];
    const float* b_comb     = (const float*)d_in[7];
    const float* g1         = (const float*)d_in[8];
    const float* be1        = (const float*)d_in[9];
    const float* g2         = (const float*)d_in[10];
    const float* be2        = (const float*)d_in[11];
    const float* w_ip       = (const float*)d_in[12];
    const float* b_ip       = (const float*)d_in[13];
    const float* theta_ffn  = (const float*)d_in[14];
    const float* w1         = (const float*)d_in[15];
    const float* b1         = (const float*)d_in[16];
    const float* w2         = (const float*)d_in[17];
    const float* b2         = (const float*)d_in[18];
    float* out = (float*)d_out;

    float* ws = (float*)d_ws;
    float* qout    = ws + 0;           // 1,048,576
    float* qkv     = ws + 1048576;     // 3,145,728
    float* ctx     = ws + 4194304;     // 1,048,576
    float* h       = ws + 5242880;     // 1,048,576
    float* weff    = ws + 6291456;     // 65,536
    float* beff    = ws + 6356992;     // 256
    float* qf      = ws + 6357248;     // 32,768
    float* attn_out = qout;
    float* t        = qkv;
    float* ffn_out  = qout;

    qout_kernel<<<(M_ * E_) / 256, 256, 0, stream>>>(x, theta_attn, qout, M_ * E_);
    weff_kernel<<<E_, E_, 0, stream>>>(w_comb, w_out, weff);
    beff_kernel<<<1, E_, 0, stream>>>(w_comb, b_out, b_comb, beff);
    gemm_kernel<<<dim3(768 / 64, M_ / 64), 256, 0, stream>>>(qout, w_in, b_in, qkv, M_, 3 * E_, E_);
    attn_mfma_kernel<<<dim3(S_ / 128, H_, B_), 256, 0, stream>>>(qkv, ctx);
    gemm_kernel<<<dim3(E_ / 64, M_ / 64), 256, 0, stream>>>(ctx, weff, beff, attn_out, M_, E_, E_);
    resid_ln_kernel<<<M_ / 4, 256, 0, stream>>>(x, attn_out, g1, be1, h);
    projqf_kernel<<<M_ / 4, 256, 0, stream>>>(h, w_ip, b_ip, theta_ffn, qf);
    ffn_t_kernel<<<(M_ * FF_) / 256, 256, 0, stream>>>(qf, w1, b1, t);
    gemm_kernel<<<dim3(E_ / 64, M_ / 64), 256, 0, stream>>>(t, w2, b2, ffn_out, M_, E_, FF_);
    resid_ln_kernel<<<M_ / 4, 256, 0, stream>>>(h, ffn_out, g2, be2, out);
}

// Round 3
// 242.589 us; speedup vs baseline: 1.7948x; 1.5237x over previous
//
#include <hip/hip_runtime.h>

#define B_  4
#define S_  1024
#define E_  256
#define H_  32
#define DK_ 8
#define NQ_ 8
#define FF_ 1024
#define M_  (B_*S_)   // 4096 tokens

typedef __attribute__((ext_vector_type(8))) short bf16x8;
typedef __attribute__((ext_vector_type(4))) short short4v;
typedef __attribute__((ext_vector_type(4))) float f32x4;

__device__ inline short f2bf(float f) {
    union { float f; unsigned u; } v; v.f = f;
    unsigned r = (v.u + 0x7fff + ((v.u >> 16) & 1)) >> 16;   // RNE
    return (short)r;
}

// ---------------- q_out = cos(x + theta[e%8]) -> bf16, 8 elems/thread ----------------
__global__ __launch_bounds__(256) void qout_kernel(const float* __restrict__ x,
                                                   const float* __restrict__ theta,
                                                   ushort* __restrict__ qout) {
    int i = blockIdx.x * 256 + threadIdx.x;          // one per 8 elements
    float4 a = ((const float4*)x)[i * 2];
    float4 b = ((const float4*)x)[i * 2 + 1];
    bf16x8 o;
    o[0] = f2bf(__cosf(a.x + theta[0]));
    o[1] = f2bf(__cosf(a.y + theta[1]));
    o[2] = f2bf(__cosf(a.z + theta[2]));
    o[3] = f2bf(__cosf(a.w + theta[3]));
    o[4] = f2bf(__cosf(b.x + theta[4]));
    o[5] = f2bf(__cosf(b.y + theta[5]));
    o[6] = f2bf(__cosf(b.z + theta[6]));
    o[7] = f2bf(__cosf(b.w + theta[7]));
    *(bf16x8*)(qout + (size_t)i * 8) = o;
}

// ---------------- fp32 -> bf16 conversion (weights), 4 elems/thread ----------------
__global__ __launch_bounds__(256) void conv_kernel(const float* __restrict__ src,
                                                   ushort* __restrict__ dst, int n4) {
    int i = blockIdx.x * 256 + threadIdx.x;
    if (i < n4) {
        float4 v = ((const float4*)src)[i];
        short4v o = {f2bf(v.x), f2bf(v.y), f2bf(v.z), f2bf(v.w)};
        ((short4v*)dst)[i] = o;
    }
}

// ---------------- w_eff = w_comb @ w_out  (E x E) -> bf16 ----------------
__global__ __launch_bounds__(256) void weff_kernel(const float* __restrict__ w_comb,
                                                   const float* __restrict__ w_out,
                                                   ushort* __restrict__ weff) {
    int i = blockIdx.x, j = threadIdx.x;
    float s = 0.f;
    for (int k = 0; k < E_; ++k) s += w_comb[i * E_ + k] * w_out[k * E_ + j];
    weff[i * E_ + j] = (ushort)f2bf(s);
}

__global__ __launch_bounds__(256) void beff_kernel(const float* __restrict__ w_comb,
                                                   const float* __restrict__ b_out,
                                                   const float* __restrict__ b_comb,
                                                   float* __restrict__ beff) {
    int i = threadIdx.x;
    float s = b_comb[i];
    for (int k = 0; k < E_; ++k) s += w_comb[i * E_ + k] * b_out[k];
    beff[i] = s;
}

// ---------------- bf16 MFMA GEMM: C[M,N] = A[M,K] @ W[N,K]^T + bias ----------------
// BM=128, BN=64, BK=64; 4 waves, each 64x32 (4x2 frags of 16x16x32)
// LDS XOR-swizzled (T2): byte ^= (row&7)<<4 on write and read
template<int OUT_BF16>
__global__ __launch_bounds__(256) void gemm_mfma_kernel(const ushort* __restrict__ A,
                                                        const ushort* __restrict__ W,
                                                        const float* __restrict__ bias,
                                                        void* __restrict__ Cv,
                                                        int Ndim, int Kdim) {
    __shared__ ushort As[128 * 64];
    __shared__ ushort Bs[64 * 64];
    int bm = blockIdx.y * 128, bn = blockIdx.x * 64;
    int tid = threadIdx.x;
    int w = tid >> 6, l = tid & 63, lq = l & 15, hi = l >> 4;
    int wm = w & 1, wn = w >> 1;
    f32x4 acc[4][2] = {};
    int srow = tid >> 3;            // 0..31
    int skb = (tid & 7) * 16;       // byte offset within 128B row

    for (int k0 = 0; k0 < Kdim; k0 += 64) {
        __syncthreads();
#pragma unroll
        for (int it = 0; it < 4; ++it) {
            int row = it * 32 + srow;
            bf16x8 v = *(const bf16x8*)(A + (size_t)(bm + row) * Kdim + k0 + (skb >> 1));
            *(bf16x8*)((char*)As + row * 128 + (skb ^ ((row & 7) << 4))) = v;
        }
#pragma unroll
        for (int it = 0; it < 2; ++it) {
            int row = it * 32 + srow;
            bf16x8 v = *(const bf16x8*)(W + (size_t)(bn + row) * Kdim + k0 + (skb >> 1));
            *(bf16x8*)((char*)Bs + row * 128 + (skb ^ ((row & 7) << 4))) = v;
        }
        __syncthreads();
#pragma unroll
        for (int kk = 0; kk < 2; ++kk) {
            bf16x8 af[4], bfr[2];
#pragma unroll
            for (int mf = 0; mf < 4; ++mf) {
                int row = wm * 64 + mf * 16 + lq;
                af[mf] = *(const bf16x8*)((const char*)As + row * 128 +
                                          ((kk * 64 + hi * 16) ^ ((row & 7) << 4)));
            }
#pragma unroll
            for (int nf = 0; nf < 2; ++nf) {
                int row = wn * 32 + nf * 16 + lq;
                bfr[nf] = *(const bf16x8*)((const char*)Bs + row * 128 +
                                           ((kk * 64 + hi * 16) ^ ((row & 7) << 4)));
            }
#pragma unroll
            for (int mf = 0; mf < 4; ++mf)
#pragma unroll
                for (int nf = 0; nf < 2; ++nf)
                    acc[mf][nf] = __builtin_amdgcn_mfma_f32_16x16x32_bf16(af[mf], bfr[nf], acc[mf][nf], 0, 0, 0);
        }
    }
#pragma unroll
    for (int mf = 0; mf < 4; ++mf)
#pragma unroll
        for (int nf = 0; nf < 2; ++nf) {
            int n = bn + wn * 32 + nf * 16 + lq;
            float bv = bias[n];
#pragma unroll
            for (int r = 0; r < 4; ++r) {
                int m = bm + wm * 64 + mf * 16 + hi * 4 + r;
                float val = acc[mf][nf][r] + bv;
                if (OUT_BF16) ((ushort*)Cv)[(size_t)m * Ndim + n] = (ushort)f2bf(val);
                else ((float*)Cv)[(size_t)m * Ndim + n] = val;
            }
        }
}

// ---------------- MFMA flash attention (bf16 qkv in, bf16 ctx out) ----------------
__global__ __launch_bounds__(256) void attn_mfma_kernel(const ushort* __restrict__ qkv,
                                                        ushort* __restrict__ ctx) {
    __shared__ ushort smem[25664];                // 51328 B
    const int KOFF = 0;                           // K  [1024][8]
    const int VTOFF = 8192;                       // V^T [8][1032]
    const int POFF = 16448;                       // P per (wave,qf): [16][72]
    int qt = blockIdx.x, h = blockIdx.y, b = blockIdx.z;
    int tid = threadIdx.x;
    const ushort* base = qkv + (size_t)b * S_ * (3 * E_);

    for (int i = tid; i < S_; i += 256) {
        const ushort* rp = base + (size_t)i * (3 * E_) + h * 8;
        bf16x8 kv = *(const bf16x8*)(rp + E_);
        bf16x8 vv = *(const bf16x8*)(rp + 2 * E_);
        *(bf16x8*)&smem[KOFF + i * 8] = kv;
#pragma unroll
        for (int d = 0; d < 8; ++d) smem[VTOFF + d * 1032 + i] = vv[d];
    }
    __syncthreads();

    int w = tid >> 6, l = tid & 63;
    int lq = l & 15, g = l >> 4;
    const float qs = 0.5100880289202462f;  // log2(e)/sqrt(8)

    bf16x8 qfrag[2];
#pragma unroll
    for (int qf = 0; qf < 2; ++qf) {
        bf16x8 qv = {};
        if (g == 0)
            qv = *(const bf16x8*)(base + (size_t)(qt * 128 + w * 32 + qf * 16 + lq) * (3 * E_) + h * 8);
        qfrag[qf] = qv;
    }

    f32x4 ctxa[2] = {{0.f,0.f,0.f,0.f},{0.f,0.f,0.f,0.f}};
    float mrun[2] = {-1e30f, -1e30f};
    float lrun[2] = {0.f, 0.f};
    ushort* Pbase0 = &smem[POFF + (w * 2 + 0) * 1152];
    ushort* Pbase1 = &smem[POFF + (w * 2 + 1) * 1152];

    for (int kt = 0; kt < 16; ++kt) {
        bf16x8 kfrag[4];
#pragma unroll
        for (int kf = 0; kf < 4; ++kf) {
            bf16x8 kv = {};
            if (g == 0) kv = *(bf16x8*)&smem[KOFF + (kt * 64 + kf * 16 + lq) * 8];
            kfrag[kf] = kv;
        }
        f32x4 st[2][4];
#pragma unroll
        for (int qf = 0; qf < 2; ++qf)
#pragma unroll
            for (int kf = 0; kf < 4; ++kf) {
                f32x4 z = {0.f, 0.f, 0.f, 0.f};
                st[qf][kf] = __builtin_amdgcn_mfma_f32_16x16x32_bf16(kfrag[kf], qfrag[qf], z, 0, 0, 0);
            }
#pragma unroll
        for (int qf = 0; qf < 2; ++qf) {
            float mt = st[qf][0][0];
#pragma unroll
            for (int kf = 0; kf < 4; ++kf)
#pragma unroll
                for (int r = 0; r < 4; ++r) mt = fmaxf(mt, st[qf][kf][r]);
            mt = fmaxf(mt, __shfl_xor(mt, 16));
            mt = fmaxf(mt, __shfl_xor(mt, 32));
            float mn = fmaxf(mrun[qf], mt * qs);
            float c = exp2f(mrun[qf] - mn);
            mrun[qf] = mn;
            float ts = 0.f;
#pragma unroll
            for (int kf = 0; kf < 4; ++kf)
#pragma unroll
                for (int r = 0; r < 4; ++r) {
                    float p = exp2f(fmaf(st[qf][kf][r], qs, -mn));
                    st[qf][kf][r] = p;
                    ts += p;
                }
            ts += __shfl_xor(ts, 16);
            ts += __shfl_xor(ts, 32);
            lrun[qf] = lrun[qf] * c + ts;
#pragma unroll
            for (int r = 0; r < 4; ++r) ctxa[qf][r] *= c;
            ushort* Pb = (qf == 0) ? Pbase0 : Pbase1;
#pragma unroll
            for (int kf = 0; kf < 4; ++kf) {
                short4v pv;
#pragma unroll
                for (int r = 0; r < 4; ++r) pv[r] = f2bf(st[qf][kf][r]);
                *(short4v*)&Pb[lq * 72 + kf * 16 + g * 4] = pv;
            }
        }
        asm volatile("s_waitcnt lgkmcnt(0)" ::: "memory");
#pragma unroll
        for (int half = 0; half < 2; ++half) {
            bf16x8 vt = *(bf16x8*)&smem[VTOFF + lq * 1032 + kt * 64 + half * 32 + g * 8];
#pragma unroll
            for (int qf = 0; qf < 2; ++qf) {
                ushort* Pb = (qf == 0) ? Pbase0 : Pbase1;
                bf16x8 pf = *(bf16x8*)&Pb[lq * 72 + half * 32 + g * 8];
                ctxa[qf] = __builtin_amdgcn_mfma_f32_16x16x32_bf16(vt, pf, ctxa[qf], 0, 0, 0);
            }
        }
    }

#pragma unroll
    for (int qf = 0; qf < 2; ++qf) {
        if (g < 2) {
            float inv = 1.f / lrun[qf];
            int token = b * S_ + qt * 128 + w * 32 + qf * 16 + lq;
            short4v o = {f2bf(ctxa[qf][0] * inv), f2bf(ctxa[qf][1] * inv),
                         f2bf(ctxa[qf][2] * inv), f2bf(ctxa[qf][3] * inv)};
            *(short4v*)(ctx + (size_t)token * E_ + h * 8 + g * 4) = o;
        }
    }
}

// ---------------- residual + layernorm (fp32) ----------------
__global__ __launch_bounds__(256) void resid_ln_kernel(const float* __restrict__ a,
                                                       const float* __restrict__ r,
                                                       const float* __restrict__ g,
                                                       const float* __restrict__ be,
                                                       float* __restrict__ out) {
    int wave = threadIdx.x >> 6, lane = threadIdx.x & 63;
    int token = blockIdx.x * 4 + wave;
    const float4 av = ((const float4*)(a + (size_t)token * E_))[lane];
    const float4 rv = ((const float4*)(r + (size_t)token * E_))[lane];
    float v0 = av.x + rv.x, v1 = av.y + rv.y, v2 = av.z + rv.z, v3 = av.w + rv.w;
    float sum = v0 + v1 + v2 + v3;
#pragma unroll
    for (int o = 32; o > 0; o >>= 1) sum += __shfl_xor(sum, o);
    float mu = sum * (1.f / E_);
    float d0 = v0 - mu, d1 = v1 - mu, d2 = v2 - mu, d3 = v3 - mu;
    float ss = d0 * d0 + d1 * d1 + d2 * d2 + d3 * d3;
#pragma unroll
    for (int o = 32; o > 0; o >>= 1) ss += __shfl_xor(ss, o);
    float rstd = rsqrtf(ss * (1.f / E_) + 1e-5f);
    float4 gv = ((const float4*)g)[lane];
    float4 bv = ((const float4*)be)[lane];
    float4 ov = make_float4(d0 * rstd * gv.x + bv.x, d1 * rstd * gv.y + bv.y,
                            d2 * rstd * gv.z + bv.z, d3 * rstd * gv.w + bv.w);
    ((float4*)(out + (size_t)token * E_))[lane] = ov;
}

// ---------------- proj + quantum ffn encoding ----------------
__global__ __launch_bounds__(256) void projqf_kernel(const float* __restrict__ h,
                                                     const float* __restrict__ w_ip,
                                                     const float* __restrict__ b_ip,
                                                     const float* __restrict__ theta,
                                                     float* __restrict__ qf) {
    int wave = threadIdx.x >> 6, lane = threadIdx.x & 63;
    int token = blockIdx.x * 4 + wave;
    float4 hv = ((const float4*)(h + (size_t)token * E_))[lane];
    float acc[8];
#pragma unroll
    for (int w = 0; w < 8; ++w) {
        float4 wv = ((const float4*)(w_ip + w * E_))[lane];
        acc[w] = hv.x * wv.x + hv.y * wv.y + hv.z * wv.z + hv.w * wv.w;
    }
#pragma unroll
    for (int o = 32; o > 0; o >>= 1) {
#pragma unroll
        for (int w = 0; w < 8; ++w) acc[w] += __shfl_xor(acc[w], o);
    }
    if (lane == 0) {
#pragma unroll
        for (int w = 0; w < 8; ++w)
            qf[(size_t)token * NQ_ + w] = __cosf(theta[w]) * __cosf(acc[w] + b_ip[w]);
    }
}

// ---------------- t = relu(qf @ w1^T + b1) -> bf16, 8 outputs/thread ----------------
__global__ __launch_bounds__(256) void ffn_t_kernel(const float* __restrict__ qf,
                                                    const float* __restrict__ w1,
                                                    const float* __restrict__ b1,
                                                    ushort* __restrict__ t) {
    int idx = blockIdx.x * 256 + threadIdx.x;   // one per 8 outputs
    int token = idx >> 7;
    int fb = (idx & 127) * 8;
    const float* qp = qf + (size_t)token * NQ_;
    float4 q0 = ((const float4*)qp)[0], q1 = ((const float4*)qp)[1];
    bf16x8 o;
#pragma unroll
    for (int j = 0; j < 8; ++j) {
        const float* wp = w1 + (size_t)(fb + j) * NQ_;
        float4 w0 = ((const float4*)wp)[0], w1v = ((const float4*)wp)[1];
        float s = b1[fb + j] + q0.x * w0.x + q0.y * w0.y + q0.z * w0.z + q0.w * w0.w
                + q1.x * w1v.x + q1.y * w1v.y + q1.z * w1v.z + q1.w * w1v.w;
        o[j] = f2bf(fmaxf(s, 0.f));
    }
    *(bf16x8*)(t + (size_t)idx * 8) = o;
}

extern "C" void kernel_launch(void* const* d_in, const int* in_sizes, int n_in,
                              void* d_out, int out_size, void* d_ws, size_t ws_size,
                              hipStream_t stream) {
    const float* x          = (const float*)d_in[0];
    const float* theta_attn = (const float*)d_in[1];
    const float* w_in       = (const float*)d_in[2];
    const float* b_in       = (const float*)d_in[3];
    const float* w_out      = (const float*)d_in[4];
    const float* b_out      = (const float*)d_in[5];
    const float* w_comb     = (const float*)d_in[6];
    const float* b_comb     = (const float*)d_in[7];
    const float* g1         = (const float*)d_in[8];
    const float* be1        = (const float*)d_in[9];
    const float* g2         = (const float*)d_in[10];
    const float* be2        = (const float*)d_in[11];
    const float* w_ip       = (const float*)d_in[12];
    const float* b_ip       = (const float*)d_in[13];
    const float* theta_ffn  = (const float*)d_in[14];
    const float* w1         = (const float*)d_in[15];
    const float* b1         = (const float*)d_in[16];
    const float* w2         = (const float*)d_in[17];
    const float* b2         = (const float*)d_in[18];
    float* out = (float*)d_out;

    char* wsb = (char*)d_ws;
    ushort* qout_bf = (ushort*)(wsb + 0);                 // 2MB [0,2MB)
    ushort* qkv_bf  = (ushort*)(wsb + (2u << 20));        // 6MB [2,8MB)
    ushort* t_bf    = (ushort*)(wsb + 0);                 // 8MB overlay [0,8MB) (qout,qkv dead)
    ushort* ctx_bf  = (ushort*)(wsb + (8u << 20));        // 2MB [8,10MB)
    float*  attn_out= (float*)(wsb + (10u << 20));        // 4MB [10,14MB)
    float*  ffn_out = attn_out;                           // reuse after LN1
    float*  h       = (float*)(wsb + (14u << 20));        // 4MB [14,18MB)
    ushort* w_in_bf = (ushort*)(wsb + (18u << 20));                 // 384KB
    ushort* w2_bf   = (ushort*)(wsb + (18u << 20) + 393216);        // 512KB
    ushort* weff_bf = (ushort*)(wsb + (18u << 20) + 917504);        // 128KB
    float*  beff    = (float*)(wsb + (19u << 20));                  // 1KB
    float*  qf      = (float*)(wsb + (19u << 20) + 4096);           // 128KB

    qout_kernel<<<(M_ * E_) / (256 * 8), 256, 0, stream>>>(x, theta_attn, qout_bf);
    conv_kernel<<<192, 256, 0, stream>>>(w_in, w_in_bf, (3 * E_ * E_) / 4);
    conv_kernel<<<256, 256, 0, stream>>>(w2, w2_bf, (E_ * FF_) / 4);
    weff_kernel<<<E_, E_, 0, stream>>>(w_comb, w_out, weff_bf);
    beff_kernel<<<1, E_, 0, stream>>>(w_comb, b_out, b_comb, beff);
    // qkv = qout @ w_in^T + b_in   [4096, 768] bf16
    gemm_mfma_kernel<1><<<dim3(768 / 64, M_ / 128), 256, 0, stream>>>(qout_bf, w_in_bf, b_in, qkv_bf, 768, E_);
    // attention -> ctx bf16
    attn_mfma_kernel<<<dim3(S_ / 128, H_, B_), 256, 0, stream>>>(qkv_bf, ctx_bf);
    // attn_out = ctx @ weff^T + beff   fp32
    gemm_mfma_kernel<0><<<dim3(E_ / 64, M_ / 128), 256, 0, stream>>>(ctx_bf, weff_bf, beff, attn_out, E_, E_);
    // h = LN(x + attn_out)
    resid_ln_kernel<<<M_ / 4, 256, 0, stream>>>(x, attn_out, g1, be1, h);
    // qf = cos(theta)*cos(h @ w_ip^T + b_ip)
    projqf_kernel<<<M_ / 4, 256, 0, stream>>>(h, w_ip, b_ip, theta_ffn, qf);
    // t = relu(qf @ w1^T + b1)  bf16
    ffn_t_kernel<<<(M_ * FF_) / (256 * 8), 256, 0, stream>>>(qf, w1, b1, t_bf);
    // ffn_out = t @ w2^T + b2   fp32
    gemm_mfma_kernel<0><<<dim3(E_ / 64, M_ / 128), 256, 0, stream>>>(t_bf, w2_bf, b2, ffn_out, E_, FF_);
    // out = LN(h + ffn_out)
    resid_ln_kernel<<<M_ / 4, 256, 0, stream>>>(h, ffn_out, g2, be2, out);
}

// Round 4
// 208.953 us; speedup vs baseline: 2.0837x; 1.1610x over previous
//
#include <hip/hip_runtime.h>
#include <hip/hip_bf16.h>

#define B_  4
#define S_  1024
#define E_  256
#define H_  32
#define DK_ 8
#define NQ_ 8
#define FF_ 1024
#define M_  (B_*S_)   // 4096 tokens
#define QS  0.5100880289202462f   // log2(e)/sqrt(8)

typedef __attribute__((ext_vector_type(8))) short bf16x8;
typedef __attribute__((ext_vector_type(4))) short short4v;
typedef __attribute__((ext_vector_type(4))) float f32x4;

__device__ inline short f2bf(float f) {
    union { float f; unsigned u; } v; v.f = f;
    unsigned r = (v.u + 0x7fff + ((v.u >> 16) & 1)) >> 16;   // RNE
    return (short)r;
}

__device__ inline unsigned pk2(float a, float b) {
    __hip_bfloat162 h = __float22bfloat162_rn(make_float2(a, b));  // x=a (low), y=b (high)
    union { __hip_bfloat162 h; unsigned u; } c; c.h = h;
    return c.u;
}

// ---------------- fused prep: qout, weight convs, transpose, b_in scale, beff ----------------
// blocks [0,512): qout  [512,704): w_in conv (+QS on q rows)  [704,960): w2 conv
// [960,1024): w_comb conv  [1024,1088): w_out transpose->bf16  [1088]: misc  [1089,1345): beff
__global__ __launch_bounds__(256) void prep_kernel(
        const float* __restrict__ x, const float* __restrict__ theta_attn,
        const float* __restrict__ w_in, const float* __restrict__ b_in,
        const float* __restrict__ w_out, const float* __restrict__ w_comb,
        const float* __restrict__ b_out, const float* __restrict__ b_comb,
        const float* __restrict__ w2,
        ushort* __restrict__ qout_bf, ushort* __restrict__ w_in_bf,
        float* __restrict__ b_in_s, ushort* __restrict__ w2_bf,
        ushort* __restrict__ w_comb_bf, ushort* __restrict__ w_outT_bf,
        float* __restrict__ zeros256, float* __restrict__ beff) {
    int blk = blockIdx.x, tid = threadIdx.x;
    __shared__ float red[4];
    if (blk < 512) {                       // q_out = cos(x + theta[e%8]) -> bf16
        int i = blk * 256 + tid;
        float4 a = ((const float4*)x)[i * 2];
        float4 b = ((const float4*)x)[i * 2 + 1];
        bf16x8 o;
        o[0] = f2bf(__cosf(a.x + theta_attn[0]));
        o[1] = f2bf(__cosf(a.y + theta_attn[1]));
        o[2] = f2bf(__cosf(a.z + theta_attn[2]));
        o[3] = f2bf(__cosf(a.w + theta_attn[3]));
        o[4] = f2bf(__cosf(b.x + theta_attn[4]));
        o[5] = f2bf(__cosf(b.y + theta_attn[5]));
        o[6] = f2bf(__cosf(b.z + theta_attn[6]));
        o[7] = f2bf(__cosf(b.w + theta_attn[7]));
        *(bf16x8*)(qout_bf + (size_t)i * 8) = o;
    } else if (blk < 704) {                // w_in -> bf16, q rows pre-scaled by QS
        int i = (blk - 512) * 256 + tid;   // [0,49152)
        float sc = (i < 16384) ? QS : 1.f;
        float4 v = ((const float4*)w_in)[i];
        short4v o = {f2bf(v.x * sc), f2bf(v.y * sc), f2bf(v.z * sc), f2bf(v.w * sc)};
        ((short4v*)w_in_bf)[i] = o;
    } else if (blk < 960) {                // w2 -> bf16
        int i = (blk - 704) * 256 + tid;   // [0,65536)
        float4 v = ((const float4*)w2)[i];
        short4v o = {f2bf(v.x), f2bf(v.y), f2bf(v.z), f2bf(v.w)};
        ((short4v*)w2_bf)[i] = o;
    } else if (blk < 1024) {               // w_comb -> bf16
        int i = (blk - 960) * 256 + tid;   // [0,16384)
        float4 v = ((const float4*)w_comb)[i];
        short4v o = {f2bf(v.x), f2bf(v.y), f2bf(v.z), f2bf(v.w)};
        ((short4v*)w_comb_bf)[i] = o;
    } else if (blk < 1088) {               // w_outT[j][k] = w_out[k][j] -> bf16
        int idx = (blk - 1024) * 256 + tid;  // [0,16384)
        int e = idx * 4, j = e >> 8, k0 = e & 255;
        short4v o;
#pragma unroll
        for (int i2 = 0; i2 < 4; ++i2) o[i2] = f2bf(w_out[(size_t)(k0 + i2) * 256 + j]);
        *(short4v*)(w_outT_bf + j * 256 + k0) = o;
    } else if (blk < 1089) {               // b_in scale + zeros
        for (int r = 0; r < 3; ++r) {
            int i = r * 256 + tid;
            b_in_s[i] = b_in[i] * ((i < 256) ? QS : 1.f);
        }
        zeros256[tid] = 0.f;
    } else {                               // beff[i] = w_comb[i,:]@b_out + b_comb[i]
        int i = blk - 1089;
        float p = w_comb[(size_t)i * 256 + tid] * b_out[tid];
#pragma unroll
        for (int o = 32; o > 0; o >>= 1) p += __shfl_xor(p, o);
        if ((tid & 63) == 0) red[tid >> 6] = p;
        __syncthreads();
        if (tid == 0) beff[i] = red[0] + red[1] + red[2] + red[3] + b_comb[i];
    }
}

// ---------------- bf16 MFMA GEMM: C[M,N] = A[M,K] @ W[N,K]^T + bias ----------------
// BM=128, BN=64, BK=64; 4 waves, each 64x32 (4x2 frags of 16x16x32); XOR-swizzled LDS
template<int OUT_BF16>
__global__ __launch_bounds__(256) void gemm_mfma_kernel(const ushort* __restrict__ A,
                                                        const ushort* __restrict__ W,
                                                        const float* __restrict__ bias,
                                                        void* __restrict__ Cv,
                                                        int Ndim, int Kdim) {
    __shared__ ushort As[128 * 64];
    __shared__ ushort Bs[64 * 64];
    int bm = blockIdx.y * 128, bn = blockIdx.x * 64;
    int tid = threadIdx.x;
    int w = tid >> 6, l = tid & 63, lq = l & 15, hi = l >> 4;
    int wm = w & 1, wn = w >> 1;
    f32x4 acc[4][2] = {};
    int srow = tid >> 3;            // 0..31
    int skb = (tid & 7) * 16;       // byte offset within 128B row

    for (int k0 = 0; k0 < Kdim; k0 += 64) {
        __syncthreads();
#pragma unroll
        for (int it = 0; it < 4; ++it) {
            int row = it * 32 + srow;
            bf16x8 v = *(const bf16x8*)(A + (size_t)(bm + row) * Kdim + k0 + (skb >> 1));
            *(bf16x8*)((char*)As + row * 128 + (skb ^ ((row & 7) << 4))) = v;
        }
#pragma unroll
        for (int it = 0; it < 2; ++it) {
            int row = it * 32 + srow;
            bf16x8 v = *(const bf16x8*)(W + (size_t)(bn + row) * Kdim + k0 + (skb >> 1));
            *(bf16x8*)((char*)Bs + row * 128 + (skb ^ ((row & 7) << 4))) = v;
        }
        __syncthreads();
#pragma unroll
        for (int kk = 0; kk < 2; ++kk) {
            bf16x8 af[4], bfr[2];
#pragma unroll
            for (int mf = 0; mf < 4; ++mf) {
                int row = wm * 64 + mf * 16 + lq;
                af[mf] = *(const bf16x8*)((const char*)As + row * 128 +
                                          ((kk * 64 + hi * 16) ^ ((row & 7) << 4)));
            }
#pragma unroll
            for (int nf = 0; nf < 2; ++nf) {
                int row = wn * 32 + nf * 16 + lq;
                bfr[nf] = *(const bf16x8*)((const char*)Bs + row * 128 +
                                           ((kk * 64 + hi * 16) ^ ((row & 7) << 4)));
            }
#pragma unroll
            for (int mf = 0; mf < 4; ++mf)
#pragma unroll
                for (int nf = 0; nf < 2; ++nf)
                    acc[mf][nf] = __builtin_amdgcn_mfma_f32_16x16x32_bf16(af[mf], bfr[nf], acc[mf][nf], 0, 0, 0);
        }
    }
#pragma unroll
    for (int mf = 0; mf < 4; ++mf)
#pragma unroll
        for (int nf = 0; nf < 2; ++nf) {
            int n = bn + wn * 32 + nf * 16 + lq;
            float bv = bias[n];
#pragma unroll
            for (int r = 0; r < 4; ++r) {
                int m = bm + wm * 64 + mf * 16 + hi * 4 + r;
                float val = acc[mf][nf][r] + bv;
                if (OUT_BF16) ((ushort*)Cv)[(size_t)m * Ndim + n] = (ushort)f2bf(val);
                else ((float*)Cv)[(size_t)m * Ndim + n] = val;
            }
        }
}

// ---------------- MFMA flash attention, no-max softmax, MFMA-sum ----------------
// Q pre-scaled by log2(e)/sqrt(8) (folded into w_in/b_in). p = exp2(score) directly.
// V^T has ones-row at d=8: PV output row 8 = sum of P per query.
__global__ __launch_bounds__(256) void attn_mfma_kernel(const ushort* __restrict__ qkv,
                                                        ushort* __restrict__ ctx) {
    __shared__ ushort smem[26696];                // 53392 B -> 3 blocks/CU
    const int KOFF = 0;                           // K  [1024][8]
    const int VTOFF = 8192;                       // V^T [9][1032], row 8 = ones
    const int POFF = 17480;                       // P per (wave,qf): [16][72]
    int qt = blockIdx.x, h = blockIdx.y, b = blockIdx.z;
    int tid = threadIdx.x;
    const ushort* base = qkv + (size_t)b * S_ * (3 * E_);

    for (int i = tid; i < S_; i += 256) {
        const ushort* rp = base + (size_t)i * (3 * E_) + h * 8;
        bf16x8 kv = *(const bf16x8*)(rp + E_);
        bf16x8 vv = *(const bf16x8*)(rp + 2 * E_);
        *(bf16x8*)&smem[KOFF + i * 8] = kv;
#pragma unroll
        for (int d = 0; d < 8; ++d) smem[VTOFF + d * 1032 + i] = vv[d];
        smem[VTOFF + 8 * 1032 + i] = 0x3F80;      // ones row (bf16 1.0)
    }
    __syncthreads();

    int w = tid >> 6, l = tid & 63;
    int lq = l & 15, g = l >> 4;

    bf16x8 qfrag[2];
#pragma unroll
    for (int qf = 0; qf < 2; ++qf) {
        bf16x8 qv = {};
        if (g == 0)
            qv = *(const bf16x8*)(base + (size_t)(qt * 128 + w * 32 + qf * 16 + lq) * (3 * E_) + h * 8);
        qfrag[qf] = qv;
    }

    f32x4 ctxa[2] = {{0.f,0.f,0.f,0.f},{0.f,0.f,0.f,0.f}};
    ushort* Pbase0 = &smem[POFF + (w * 2 + 0) * 1152];
    ushort* Pbase1 = &smem[POFF + (w * 2 + 1) * 1152];

    for (int kt = 0; kt < 16; ++kt) {
        bf16x8 kfrag[4];
#pragma unroll
        for (int kf = 0; kf < 4; ++kf) {
            bf16x8 kv = {};
            if (g == 0) kv = *(bf16x8*)&smem[KOFF + (kt * 64 + kf * 16 + lq) * 8];
            kfrag[kf] = kv;
        }
        f32x4 st[2][4];
#pragma unroll
        for (int qf = 0; qf < 2; ++qf)
#pragma unroll
            for (int kf = 0; kf < 4; ++kf) {
                f32x4 z = {0.f, 0.f, 0.f, 0.f};
                st[qf][kf] = __builtin_amdgcn_mfma_f32_16x16x32_bf16(kfrag[kf], qfrag[qf], z, 0, 0, 0);
            }
#pragma unroll
        for (int qf = 0; qf < 2; ++qf) {
            ushort* Pb = (qf == 0) ? Pbase0 : Pbase1;
#pragma unroll
            for (int kf = 0; kf < 4; ++kf) {
                uint2 pw;
                pw.x = pk2(exp2f(st[qf][kf][0]), exp2f(st[qf][kf][1]));
                pw.y = pk2(exp2f(st[qf][kf][2]), exp2f(st[qf][kf][3]));
                *(uint2*)&Pb[lq * 72 + kf * 16 + g * 4] = pw;
            }
        }
        asm volatile("s_waitcnt lgkmcnt(0)" ::: "memory");
#pragma unroll
        for (int half = 0; half < 2; ++half) {
            bf16x8 vt = *(bf16x8*)&smem[VTOFF + lq * 1032 + kt * 64 + half * 32 + g * 8];
#pragma unroll
            for (int qf = 0; qf < 2; ++qf) {
                ushort* Pb = (qf == 0) ? Pbase0 : Pbase1;
                bf16x8 pf = *(bf16x8*)&Pb[lq * 72 + half * 32 + g * 8];
                ctxa[qf] = __builtin_amdgcn_mfma_f32_16x16x32_bf16(vt, pf, ctxa[qf], 0, 0, 0);
            }
        }
    }

#pragma unroll
    for (int qf = 0; qf < 2; ++qf) {
        float lsum = __shfl(ctxa[qf][0], 32 + lq);   // row 8 (sum) lives at lane g=2,r=0
        float inv = 1.f / lsum;
        if (g < 2) {
            int token = b * S_ + qt * 128 + w * 32 + qf * 16 + lq;
            short4v o = {f2bf(ctxa[qf][0] * inv), f2bf(ctxa[qf][1] * inv),
                         f2bf(ctxa[qf][2] * inv), f2bf(ctxa[qf][3] * inv)};
            *(short4v*)(ctx + (size_t)token * E_ + h * 8 + g * 4) = o;
        }
    }
}

// ---------------- residual + layernorm (fp32) ----------------
__global__ __launch_bounds__(256) void resid_ln_kernel(const float* __restrict__ a,
                                                       const float* __restrict__ r,
                                                       const float* __restrict__ g,
                                                       const float* __restrict__ be,
                                                       float* __restrict__ out) {
    int wave = threadIdx.x >> 6, lane = threadIdx.x & 63;
    int token = blockIdx.x * 4 + wave;
    const float4 av = ((const float4*)(a + (size_t)token * E_))[lane];
    const float4 rv = ((const float4*)(r + (size_t)token * E_))[lane];
    float v0 = av.x + rv.x, v1 = av.y + rv.y, v2 = av.z + rv.z, v3 = av.w + rv.w;
    float sum = v0 + v1 + v2 + v3;
#pragma unroll
    for (int o = 32; o > 0; o >>= 1) sum += __shfl_xor(sum, o);
    float mu = sum * (1.f / E_);
    float d0 = v0 - mu, d1 = v1 - mu, d2 = v2 - mu, d3 = v3 - mu;
    float ss = d0 * d0 + d1 * d1 + d2 * d2 + d3 * d3;
#pragma unroll
    for (int o = 32; o > 0; o >>= 1) ss += __shfl_xor(ss, o);
    float rstd = rsqrtf(ss * (1.f / E_) + 1e-5f);
    float4 gv = ((const float4*)g)[lane];
    float4 bv = ((const float4*)be)[lane];
    float4 ov = make_float4(d0 * rstd * gv.x + bv.x, d1 * rstd * gv.y + bv.y,
                            d2 * rstd * gv.z + bv.z, d3 * rstd * gv.w + bv.w);
    ((float4*)(out + (size_t)token * E_))[lane] = ov;
}

// ---------------- proj + quantum ffn encoding ----------------
__global__ __launch_bounds__(256) void projqf_kernel(const float* __restrict__ h,
                                                     const float* __restrict__ w_ip,
                                                     const float* __restrict__ b_ip,
                                                     const float* __restrict__ theta,
                                                     float* __restrict__ qf) {
    int wave = threadIdx.x >> 6, lane = threadIdx.x & 63;
    int token = blockIdx.x * 4 + wave;
    float4 hv = ((const float4*)(h + (size_t)token * E_))[lane];
    float acc[8];
#pragma unroll
    for (int w = 0; w < 8; ++w) {
        float4 wv = ((const float4*)(w_ip + w * E_))[lane];
        acc[w] = hv.x * wv.x + hv.y * wv.y + hv.z * wv.z + hv.w * wv.w;
    }
#pragma unroll
    for (int o = 32; o > 0; o >>= 1) {
#pragma unroll
        for (int w = 0; w < 8; ++w) acc[w] += __shfl_xor(acc[w], o);
    }
    if (lane == 0) {
#pragma unroll
        for (int w = 0; w < 8; ++w)
            qf[(size_t)token * NQ_ + w] = __cosf(theta[w]) * __cosf(acc[w] + b_ip[w]);
    }
}

// ---------------- t = relu(qf @ w1^T + b1) -> bf16, 8 outputs/thread ----------------
__global__ __launch_bounds__(256) void ffn_t_kernel(const float* __restrict__ qf,
                                                    const float* __restrict__ w1,
                                                    const float* __restrict__ b1,
                                                    ushort* __restrict__ t) {
    int idx = blockIdx.x * 256 + threadIdx.x;
    int token = idx >> 7;
    int fb = (idx & 127) * 8;
    const float* qp = qf + (size_t)token * NQ_;
    float4 q0 = ((const float4*)qp)[0], q1 = ((const float4*)qp)[1];
    bf16x8 o;
#pragma unroll
    for (int j = 0; j < 8; ++j) {
        const float* wp = w1 + (size_t)(fb + j) * NQ_;
        float4 w0 = ((const float4*)wp)[0], w1v = ((const float4*)wp)[1];
        float s = b1[fb + j] + q0.x * w0.x + q0.y * w0.y + q0.z * w0.z + q0.w * w0.w
                + q1.x * w1v.x + q1.y * w1v.y + q1.z * w1v.z + q1.w * w1v.w;
        o[j] = f2bf(fmaxf(s, 0.f));
    }
    *(bf16x8*)(t + (size_t)idx * 8) = o;
}

extern "C" void kernel_launch(void* const* d_in, const int* in_sizes, int n_in,
                              void* d_out, int out_size, void* d_ws, size_t ws_size,
                              hipStream_t stream) {
    const float* x          = (const float*)d_in[0];
    const float* theta_attn = (const float*)d_in[1];
    const float* w_in       = (const float*)d_in[2];
    const float* b_in       = (const float*)d_in[3];
    const float* w_out      = (const float*)d_in[4];
    const float* b_out      = (const float*)d_in[5];
    const float* w_comb     = (const float*)d_in[6];
    const float* b_comb     = (const float*)d_in[7];
    const float* g1         = (const float*)d_in[8];
    const float* be1        = (const float*)d_in[9];
    const float* g2         = (const float*)d_in[10];
    const float* be2        = (const float*)d_in[11];
    const float* w_ip       = (const float*)d_in[12];
    const float* b_ip       = (const float*)d_in[13];
    const float* theta_ffn  = (const float*)d_in[14];
    const float* w1         = (const float*)d_in[15];
    const float* b1         = (const float*)d_in[16];
    const float* w2         = (const float*)d_in[17];
    const float* b2         = (const float*)d_in[18];
    float* out = (float*)d_out;

    char* wsb = (char*)d_ws;
    ushort* qout_bf  = (ushort*)(wsb + 0);                  // [0,2MB)
    ushort* qkv_bf   = (ushort*)(wsb + (2u << 20));         // [2,8MB)
    ushort* t_bf     = (ushort*)(wsb + 0);                  // overlay [0,8MB)
    ushort* ctx_bf   = (ushort*)(wsb + (8u << 20));         // [8,10MB)
    ushort* w_comb_bf= (ushort*)(wsb + (8u << 20));         // overlay: dead before attn writes ctx
    ushort* w_outT_bf= (ushort*)(wsb + (8u << 20) + 131072);
    float*  attn_out = (float*)(wsb + (10u << 20));         // [10,14MB)
    float*  ffn_out  = attn_out;
    float*  h        = (float*)(wsb + (14u << 20));         // [14,18MB)
    ushort* w_in_bf  = (ushort*)(wsb + (18u << 20));                  // 384KB
    ushort* w2_bf    = (ushort*)(wsb + (18u << 20) + 393216);         // 512KB
    ushort* weff_bf  = (ushort*)(wsb + (18u << 20) + 917504);         // 128KB
    float*  beff     = (float*)(wsb + (18u << 20) + 1048576);         // 1KB
    float*  zeros256 = (float*)(wsb + (18u << 20) + 1052672);         // 1KB
    float*  b_in_s   = (float*)(wsb + (18u << 20) + 1056768);         // 3KB
    float*  qf       = (float*)(wsb + (18u << 20) + 1060864);         // 128KB

    // 1) all prep: qout, convs, transpose, b_in scale, beff
    prep_kernel<<<1345, 256, 0, stream>>>(x, theta_attn, w_in, b_in, w_out, w_comb,
                                          b_out, b_comb, w2,
                                          qout_bf, w_in_bf, b_in_s, w2_bf,
                                          w_comb_bf, w_outT_bf, zeros256, beff);
    // 2) weff = w_comb @ w_out (via w_out^T), bf16
    gemm_mfma_kernel<1><<<dim3(4, 2), 256, 0, stream>>>(w_comb_bf, w_outT_bf, zeros256, weff_bf, E_, E_);
    // 3) qkv = qout @ w_in_s^T + b_in_s  (q pre-scaled)
    gemm_mfma_kernel<1><<<dim3(768 / 64, M_ / 128), 256, 0, stream>>>(qout_bf, w_in_bf, b_in_s, qkv_bf, 768, E_);
    // 4) attention
    attn_mfma_kernel<<<dim3(S_ / 128, H_, B_), 256, 0, stream>>>(qkv_bf, ctx_bf);
    // 5) attn_out = ctx @ weff^T + beff
    gemm_mfma_kernel<0><<<dim3(E_ / 64, M_ / 128), 256, 0, stream>>>(ctx_bf, weff_bf, beff, attn_out, E_, E_);
    // 6) h = LN(x + attn_out)
    resid_ln_kernel<<<M_ / 4, 256, 0, stream>>>(x, attn_out, g1, be1, h);
    // 7) qf
    projqf_kernel<<<M_ / 4, 256, 0, stream>>>(h, w_ip, b_ip, theta_ffn, qf);
    // 8) t = relu(qf @ w1^T + b1)
    ffn_t_kernel<<<(M_ * FF_) / (256 * 8), 256, 0, stream>>>(qf, w1, b1, t_bf);
    // 9) ffn_out = t @ w2^T + b2
    gemm_mfma_kernel<0><<<dim3(E_ / 64, M_ / 128), 256, 0, stream>>>(t_bf, w2_bf, b2, ffn_out, E_, FF_);
    // 10) out = LN(h + ffn_out)
    resid_ln_kernel<<<M_ / 4, 256, 0, stream>>>(h, ffn_out, g2, be2, out);
}

// Round 5
// 204.923 us; speedup vs baseline: 2.1247x; 1.0197x over previous
//
#include <hip/hip_runtime.h>
#include <hip/hip_bf16.h>

#define B_  4
#define S_  1024
#define E_  256
#define H_  32
#define DK_ 8
#define NQ_ 8
#define FF_ 1024
#define M_  (B_*S_)   // 4096 tokens
#define QS  0.5100880289202462f   // log2(e)/sqrt(8)
#define VSTRIDE 1036              // V^T row stride in shorts (conflict-free b128 reads)

typedef __attribute__((ext_vector_type(8))) short bf16x8;
typedef __attribute__((ext_vector_type(4))) short short4v;
typedef __attribute__((ext_vector_type(4))) float f32x4;

__device__ inline short f2bf(float f) {
    union { float f; unsigned u; } v; v.f = f;
    unsigned r = (v.u + 0x7fff + ((v.u >> 16) & 1)) >> 16;   // RNE
    return (short)r;
}

__device__ inline unsigned pk2(float a, float b) {
    __hip_bfloat162 h = __float22bfloat162_rn(make_float2(a, b));  // x=a low, y=b high
    union { __hip_bfloat162 h; unsigned u; } c; c.h = h;
    return c.u;
}

// ---------------- fused prep: qout, weight convs, transpose, b_in scale, beff ----------------
__global__ __launch_bounds__(256) void prep_kernel(
        const float* __restrict__ x, const float* __restrict__ theta_attn,
        const float* __restrict__ w_in, const float* __restrict__ b_in,
        const float* __restrict__ w_out, const float* __restrict__ w_comb,
        const float* __restrict__ b_out, const float* __restrict__ b_comb,
        const float* __restrict__ w2,
        ushort* __restrict__ qout_bf, ushort* __restrict__ w_in_bf,
        float* __restrict__ b_in_s, ushort* __restrict__ w2_bf,
        ushort* __restrict__ w_comb_bf, ushort* __restrict__ w_outT_bf,
        float* __restrict__ zeros256, float* __restrict__ beff) {
    int blk = blockIdx.x, tid = threadIdx.x;
    __shared__ float red[4];
    if (blk < 512) {                       // q_out = cos(x + theta[e%8]) -> bf16
        int i = blk * 256 + tid;
        float4 a = ((const float4*)x)[i * 2];
        float4 b = ((const float4*)x)[i * 2 + 1];
        bf16x8 o;
        o[0] = f2bf(__cosf(a.x + theta_attn[0]));
        o[1] = f2bf(__cosf(a.y + theta_attn[1]));
        o[2] = f2bf(__cosf(a.z + theta_attn[2]));
        o[3] = f2bf(__cosf(a.w + theta_attn[3]));
        o[4] = f2bf(__cosf(b.x + theta_attn[4]));
        o[5] = f2bf(__cosf(b.y + theta_attn[5]));
        o[6] = f2bf(__cosf(b.z + theta_attn[6]));
        o[7] = f2bf(__cosf(b.w + theta_attn[7]));
        *(bf16x8*)(qout_bf + (size_t)i * 8) = o;
    } else if (blk < 704) {                // w_in -> bf16, q rows pre-scaled by QS
        int i = (blk - 512) * 256 + tid;
        float sc = (i < 16384) ? QS : 1.f;
        float4 v = ((const float4*)w_in)[i];
        short4v o = {f2bf(v.x * sc), f2bf(v.y * sc), f2bf(v.z * sc), f2bf(v.w * sc)};
        ((short4v*)w_in_bf)[i] = o;
    } else if (blk < 960) {                // w2 -> bf16
        int i = (blk - 704) * 256 + tid;
        float4 v = ((const float4*)w2)[i];
        short4v o = {f2bf(v.x), f2bf(v.y), f2bf(v.z), f2bf(v.w)};
        ((short4v*)w2_bf)[i] = o;
    } else if (blk < 1024) {               // w_comb -> bf16
        int i = (blk - 960) * 256 + tid;
        float4 v = ((const float4*)w_comb)[i];
        short4v o = {f2bf(v.x), f2bf(v.y), f2bf(v.z), f2bf(v.w)};
        ((short4v*)w_comb_bf)[i] = o;
    } else if (blk < 1088) {               // w_outT[j][k] = w_out[k][j] -> bf16
        int idx = (blk - 1024) * 256 + tid;
        int e = idx * 4, j = e >> 8, k0 = e & 255;
        short4v o;
#pragma unroll
        for (int i2 = 0; i2 < 4; ++i2) o[i2] = f2bf(w_out[(size_t)(k0 + i2) * 256 + j]);
        *(short4v*)(w_outT_bf + j * 256 + k0) = o;
    } else if (blk < 1089) {               // b_in scale + zeros
        for (int r = 0; r < 3; ++r) {
            int i = r * 256 + tid;
            b_in_s[i] = b_in[i] * ((i < 256) ? QS : 1.f);
        }
        zeros256[tid] = 0.f;
    } else {                               // beff[i] = w_comb[i,:]@b_out + b_comb[i]
        int i = blk - 1089;
        float p = w_comb[(size_t)i * 256 + tid] * b_out[tid];
#pragma unroll
        for (int o = 32; o > 0; o >>= 1) p += __shfl_xor(p, o);
        if ((tid & 63) == 0) red[tid >> 6] = p;
        __syncthreads();
        if (tid == 0) beff[i] = red[0] + red[1] + red[2] + red[3] + b_comb[i];
    }
}

// ---------------- bf16 MFMA GEMM: C[M,N] = A[M,K] @ W[N,K]^T + bias ----------------
template<int OUT_BF16>
__global__ __launch_bounds__(256) void gemm_mfma_kernel(const ushort* __restrict__ A,
                                                        const ushort* __restrict__ W,
                                                        const float* __restrict__ bias,
                                                        void* __restrict__ Cv,
                                                        int Ndim, int Kdim) {
    __shared__ ushort As[128 * 64];
    __shared__ ushort Bs[64 * 64];
    int bm = blockIdx.y * 128, bn = blockIdx.x * 64;
    int tid = threadIdx.x;
    int w = tid >> 6, l = tid & 63, lq = l & 15, hi = l >> 4;
    int wm = w & 1, wn = w >> 1;
    f32x4 acc[4][2] = {};
    int srow = tid >> 3;
    int skb = (tid & 7) * 16;

    for (int k0 = 0; k0 < Kdim; k0 += 64) {
        __syncthreads();
#pragma unroll
        for (int it = 0; it < 4; ++it) {
            int row = it * 32 + srow;
            bf16x8 v = *(const bf16x8*)(A + (size_t)(bm + row) * Kdim + k0 + (skb >> 1));
            *(bf16x8*)((char*)As + row * 128 + (skb ^ ((row & 7) << 4))) = v;
        }
#pragma unroll
        for (int it = 0; it < 2; ++it) {
            int row = it * 32 + srow;
            bf16x8 v = *(const bf16x8*)(W + (size_t)(bn + row) * Kdim + k0 + (skb >> 1));
            *(bf16x8*)((char*)Bs + row * 128 + (skb ^ ((row & 7) << 4))) = v;
        }
        __syncthreads();
#pragma unroll
        for (int kk = 0; kk < 2; ++kk) {
            bf16x8 af[4], bfr[2];
#pragma unroll
            for (int mf = 0; mf < 4; ++mf) {
                int row = wm * 64 + mf * 16 + lq;
                af[mf] = *(const bf16x8*)((const char*)As + row * 128 +
                                          ((kk * 64 + hi * 16) ^ ((row & 7) << 4)));
            }
#pragma unroll
            for (int nf = 0; nf < 2; ++nf) {
                int row = wn * 32 + nf * 16 + lq;
                bfr[nf] = *(const bf16x8*)((const char*)Bs + row * 128 +
                                           ((kk * 64 + hi * 16) ^ ((row & 7) << 4)));
            }
#pragma unroll
            for (int mf = 0; mf < 4; ++mf)
#pragma unroll
                for (int nf = 0; nf < 2; ++nf)
                    acc[mf][nf] = __builtin_amdgcn_mfma_f32_16x16x32_bf16(af[mf], bfr[nf], acc[mf][nf], 0, 0, 0);
        }
    }
#pragma unroll
    for (int mf = 0; mf < 4; ++mf)
#pragma unroll
        for (int nf = 0; nf < 2; ++nf) {
            int n = bn + wn * 32 + nf * 16 + lq;
            float bv = bias[n];
#pragma unroll
            for (int r = 0; r < 4; ++r) {
                int m = bm + wm * 64 + mf * 16 + hi * 4 + r;
                float val = acc[mf][nf][r] + bv;
                if (OUT_BF16) ((ushort*)Cv)[(size_t)m * Ndim + n] = (ushort)f2bf(val);
                else ((float*)Cv)[(size_t)m * Ndim + n] = val;
            }
        }
}

// ---------------- MFMA flash attention: zero-shuffle PV, no P-LDS, no K-LDS ----------------
// QK^T: scoresT = mfma(A=K, B=Q): lane(q=l&15, hi) holds keys kf*16+hi*4+r.
// V^T staged in PV-permuted key order: pv = (kf>>1)*32 + hi*8 + (kf&1)*4 + s, so the
// packed exp-scores ARE the PV A-fragment. PV: D[q][d] = mfma(A=P^T, B=V^T-row-reads).
// Ones-row at d=8 gives the softmax denominator in column 8.
__global__ __launch_bounds__(256, 4) void attn_mfma_kernel(const ushort* __restrict__ qkv,
                                                           ushort* __restrict__ ctx) {
    __shared__ ushort vt[9 * VSTRIDE + 4];     // 18664 B
    int qt = blockIdx.x, h = blockIdx.y, b = blockIdx.z;
    int tid = threadIdx.x;
    const ushort* base = qkv + (size_t)b * S_ * (3 * E_) + h * 8;

    for (int i = tid; i < S_; i += 256) {
        bf16x8 vv = *(const bf16x8*)(base + (size_t)i * (3 * E_) + 2 * E_);
        int kf = (i >> 4) & 3, hh = (i >> 2) & 3, s = i & 3;
        int pv = (i & ~63) + ((kf >> 1) << 5) + (hh << 3) + ((kf & 1) << 2) + s;
#pragma unroll
        for (int d = 0; d < 8; ++d) vt[d * VSTRIDE + pv] = vv[d];
        vt[8 * VSTRIDE + pv] = 0x3F80;         // bf16 1.0
    }
    __syncthreads();

    int w = tid >> 6, l = tid & 63, lq = l & 15, g = l >> 4;

    bf16x8 qfrag[2];
#pragma unroll
    for (int qf = 0; qf < 2; ++qf) {
        bf16x8 qv = {};
        if (g == 0)
            qv = *(const bf16x8*)(base + (size_t)(qt * 128 + w * 32 + qf * 16 + lq) * (3 * E_));
        qfrag[qf] = qv;
    }

    f32x4 ctxa[2] = {{0.f,0.f,0.f,0.f},{0.f,0.f,0.f,0.f}};

    for (int kt = 0; kt < 16; ++kt) {
        bf16x8 kfrag[4];
#pragma unroll
        for (int kf = 0; kf < 4; ++kf) {
            bf16x8 kv = {};
            if (g == 0)
                kv = *(const bf16x8*)(base + (size_t)(kt * 64 + kf * 16 + lq) * (3 * E_) + E_);
            kfrag[kf] = kv;
        }
        bf16x8 vf0 = *(bf16x8*)&vt[lq * VSTRIDE + kt * 64 + g * 8];
        bf16x8 vf1 = *(bf16x8*)&vt[lq * VSTRIDE + kt * 64 + 32 + g * 8];
#pragma unroll
        for (int qf = 0; qf < 2; ++qf) {
            f32x4 st[4];
#pragma unroll
            for (int kf = 0; kf < 4; ++kf) {
                f32x4 z = {0.f, 0.f, 0.f, 0.f};
                st[kf] = __builtin_amdgcn_mfma_f32_16x16x32_bf16(kfrag[kf], qfrag[qf], z, 0, 0, 0);
            }
            union { unsigned u[4]; bf16x8 v; } p0, p1;
            p0.u[0] = pk2(exp2f(st[0][0]), exp2f(st[0][1]));
            p0.u[1] = pk2(exp2f(st[0][2]), exp2f(st[0][3]));
            p0.u[2] = pk2(exp2f(st[1][0]), exp2f(st[1][1]));
            p0.u[3] = pk2(exp2f(st[1][2]), exp2f(st[1][3]));
            p1.u[0] = pk2(exp2f(st[2][0]), exp2f(st[2][1]));
            p1.u[1] = pk2(exp2f(st[2][2]), exp2f(st[2][3]));
            p1.u[2] = pk2(exp2f(st[3][0]), exp2f(st[3][1]));
            p1.u[3] = pk2(exp2f(st[3][2]), exp2f(st[3][3]));
            ctxa[qf] = __builtin_amdgcn_mfma_f32_16x16x32_bf16(p0.v, vf0, ctxa[qf], 0, 0, 0);
            ctxa[qf] = __builtin_amdgcn_mfma_f32_16x16x32_bf16(p1.v, vf1, ctxa[qf], 0, 0, 0);
        }
    }

    // D[q][d]: lane (d=lq, hi=g) holds q = g*4+r. Sum in column d=8.
#pragma unroll
    for (int qf = 0; qf < 2; ++qf) {
        int src = (l & 48) + 8;
        float s0 = __shfl(ctxa[qf][0], src);
        float s1 = __shfl(ctxa[qf][1], src);
        float s2 = __shfl(ctxa[qf][2], src);
        float s3 = __shfl(ctxa[qf][3], src);
        if (lq < 8) {
            int tok = b * S_ + qt * 128 + w * 32 + qf * 16 + g * 4;
            ushort* cp = ctx + (size_t)tok * E_ + h * 8 + lq;
            cp[0]       = (ushort)f2bf(ctxa[qf][0] / s0);
            cp[E_]      = (ushort)f2bf(ctxa[qf][1] / s1);
            cp[2 * E_]  = (ushort)f2bf(ctxa[qf][2] / s2);
            cp[3 * E_]  = (ushort)f2bf(ctxa[qf][3] / s3);
        }
    }
}

// ---------------- fused residual + LN1 + FFN input-proj + quantum encoding ----------------
__global__ __launch_bounds__(256) void ln1_projqf_kernel(const float* __restrict__ a,
                                                         const float* __restrict__ r,
                                                         const float* __restrict__ g,
                                                         const float* __restrict__ be,
                                                         const float* __restrict__ w_ip,
                                                         const float* __restrict__ b_ip,
                                                         const float* __restrict__ theta,
                                                         float* __restrict__ h,
                                                         float* __restrict__ qf) {
    int wave = threadIdx.x >> 6, lane = threadIdx.x & 63;
    int token = blockIdx.x * 4 + wave;
    const float4 av = ((const float4*)(a + (size_t)token * E_))[lane];
    const float4 rv = ((const float4*)(r + (size_t)token * E_))[lane];
    float v0 = av.x + rv.x, v1 = av.y + rv.y, v2 = av.z + rv.z, v3 = av.w + rv.w;
    float sum = v0 + v1 + v2 + v3;
#pragma unroll
    for (int o = 32; o > 0; o >>= 1) sum += __shfl_xor(sum, o);
    float mu = sum * (1.f / E_);
    float d0 = v0 - mu, d1 = v1 - mu, d2 = v2 - mu, d3 = v3 - mu;
    float ss = d0 * d0 + d1 * d1 + d2 * d2 + d3 * d3;
#pragma unroll
    for (int o = 32; o > 0; o >>= 1) ss += __shfl_xor(ss, o);
    float rstd = rsqrtf(ss * (1.f / E_) + 1e-5f);
    float4 gv = ((const float4*)g)[lane];
    float4 bv = ((const float4*)be)[lane];
    float4 hv = make_float4(d0 * rstd * gv.x + bv.x, d1 * rstd * gv.y + bv.y,
                            d2 * rstd * gv.z + bv.z, d3 * rstd * gv.w + bv.w);
    ((float4*)(h + (size_t)token * E_))[lane] = hv;
    // FFN input proj + quantum encoding
    float acc[8];
#pragma unroll
    for (int w = 0; w < 8; ++w) {
        float4 wv = ((const float4*)(w_ip + w * E_))[lane];
        acc[w] = hv.x * wv.x + hv.y * wv.y + hv.z * wv.z + hv.w * wv.w;
    }
#pragma unroll
    for (int o = 32; o > 0; o >>= 1) {
#pragma unroll
        for (int w = 0; w < 8; ++w) acc[w] += __shfl_xor(acc[w], o);
    }
    if (lane == 0) {
#pragma unroll
        for (int w = 0; w < 8; ++w)
            qf[(size_t)token * NQ_ + w] = __cosf(theta[w]) * __cosf(acc[w] + b_ip[w]);
    }
}

// ---------------- residual + layernorm (fp32) — final ----------------
__global__ __launch_bounds__(256) void resid_ln_kernel(const float* __restrict__ a,
                                                       const float* __restrict__ r,
                                                       const float* __restrict__ g,
                                                       const float* __restrict__ be,
                                                       float* __restrict__ out) {
    int wave = threadIdx.x >> 6, lane = threadIdx.x & 63;
    int token = blockIdx.x * 4 + wave;
    const float4 av = ((const float4*)(a + (size_t)token * E_))[lane];
    const float4 rv = ((const float4*)(r + (size_t)token * E_))[lane];
    float v0 = av.x + rv.x, v1 = av.y + rv.y, v2 = av.z + rv.z, v3 = av.w + rv.w;
    float sum = v0 + v1 + v2 + v3;
#pragma unroll
    for (int o = 32; o > 0; o >>= 1) sum += __shfl_xor(sum, o);
    float mu = sum * (1.f / E_);
    float d0 = v0 - mu, d1 = v1 - mu, d2 = v2 - mu, d3 = v3 - mu;
    float ss = d0 * d0 + d1 * d1 + d2 * d2 + d3 * d3;
#pragma unroll
    for (int o = 32; o > 0; o >>= 1) ss += __shfl_xor(ss, o);
    float rstd = rsqrtf(ss * (1.f / E_) + 1e-5f);
    float4 gv = ((const float4*)g)[lane];
    float4 bv = ((const float4*)be)[lane];
    float4 ov = make_float4(d0 * rstd * gv.x + bv.x, d1 * rstd * gv.y + bv.y,
                            d2 * rstd * gv.z + bv.z, d3 * rstd * gv.w + bv.w);
    ((float4*)(out + (size_t)token * E_))[lane] = ov;
}

// ---------------- t = relu(qf @ w1^T + b1) -> bf16, 8 outputs/thread ----------------
__global__ __launch_bounds__(256) void ffn_t_kernel(const float* __restrict__ qf,
                                                    const float* __restrict__ w1,
                                                    const float* __restrict__ b1,
                                                    ushort* __restrict__ t) {
    int idx = blockIdx.x * 256 + threadIdx.x;
    int token = idx >> 7;
    int fb = (idx & 127) * 8;
    const float* qp = qf + (size_t)token * NQ_;
    float4 q0 = ((const float4*)qp)[0], q1 = ((const float4*)qp)[1];
    bf16x8 o;
#pragma unroll
    for (int j = 0; j < 8; ++j) {
        const float* wp = w1 + (size_t)(fb + j) * NQ_;
        float4 w0 = ((const float4*)wp)[0], w1v = ((const float4*)wp)[1];
        float s = b1[fb + j] + q0.x * w0.x + q0.y * w0.y + q0.z * w0.z + q0.w * w0.w
                + q1.x * w1v.x + q1.y * w1v.y + q1.z * w1v.z + q1.w * w1v.w;
        o[j] = f2bf(fmaxf(s, 0.f));
    }
    *(bf16x8*)(t + (size_t)idx * 8) = o;
}

extern "C" void kernel_launch(void* const* d_in, const int* in_sizes, int n_in,
                              void* d_out, int out_size, void* d_ws, size_t ws_size,
                              hipStream_t stream) {
    const float* x          = (const float*)d_in[0];
    const float* theta_attn = (const float*)d_in[1];
    const float* w_in       = (const float*)d_in[2];
    const float* b_in       = (const float*)d_in[3];
    const float* w_out      = (const float*)d_in[4];
    const float* b_out      = (const float*)d_in[5];
    const float* w_comb     = (const float*)d_in[6];
    const float* b_comb     = (const float*)d_in[7];
    const float* g1         = (const float*)d_in[8];
    const float* be1        = (const float*)d_in[9];
    const float* g2         = (const float*)d_in[10];
    const float* be2        = (const float*)d_in[11];
    const float* w_ip       = (const float*)d_in[12];
    const float* b_ip       = (const float*)d_in[13];
    const float* theta_ffn  = (const float*)d_in[14];
    const float* w1         = (const float*)d_in[15];
    const float* b1         = (const float*)d_in[16];
    const float* w2         = (const float*)d_in[17];
    const float* b2         = (const float*)d_in[18];
    float* out = (float*)d_out;

    char* wsb = (char*)d_ws;
    ushort* qout_bf  = (ushort*)(wsb + 0);                  // [0,2MB)
    ushort* qkv_bf   = (ushort*)(wsb + (2u << 20));         // [2,8MB)
    ushort* t_bf     = (ushort*)(wsb + 0);                  // overlay [0,8MB)
    ushort* ctx_bf   = (ushort*)(wsb + (8u << 20));         // [8,10MB)
    ushort* w_comb_bf= (ushort*)(wsb + (8u << 20));         // overlay: dead before ctx written
    ushort* w_outT_bf= (ushort*)(wsb + (8u << 20) + 131072);
    float*  attn_out = (float*)(wsb + (10u << 20));         // [10,14MB)
    float*  ffn_out  = attn_out;
    float*  h        = (float*)(wsb + (14u << 20));         // [14,18MB)
    ushort* w_in_bf  = (ushort*)(wsb + (18u << 20));
    ushort* w2_bf    = (ushort*)(wsb + (18u << 20) + 393216);
    ushort* weff_bf  = (ushort*)(wsb + (18u << 20) + 917504);
    float*  beff     = (float*)(wsb + (18u << 20) + 1048576);
    float*  zeros256 = (float*)(wsb + (18u << 20) + 1052672);
    float*  b_in_s   = (float*)(wsb + (18u << 20) + 1056768);
    float*  qf       = (float*)(wsb + (18u << 20) + 1060864);

    prep_kernel<<<1345, 256, 0, stream>>>(x, theta_attn, w_in, b_in, w_out, w_comb,
                                          b_out, b_comb, w2,
                                          qout_bf, w_in_bf, b_in_s, w2_bf,
                                          w_comb_bf, w_outT_bf, zeros256, beff);
    gemm_mfma_kernel<1><<<dim3(4, 2), 256, 0, stream>>>(w_comb_bf, w_outT_bf, zeros256, weff_bf, E_, E_);
    gemm_mfma_kernel<1><<<dim3(768 / 64, M_ / 128), 256, 0, stream>>>(qout_bf, w_in_bf, b_in_s, qkv_bf, 768, E_);
    attn_mfma_kernel<<<dim3(S_ / 128, H_, B_), 256, 0, stream>>>(qkv_bf, ctx_bf);
    gemm_mfma_kernel<0><<<dim3(E_ / 64, M_ / 128), 256, 0, stream>>>(ctx_bf, weff_bf, beff, attn_out, E_, E_);
    ln1_projqf_kernel<<<M_ / 4, 256, 0, stream>>>(x, attn_out, g1, be1, w_ip, b_ip, theta_ffn, h, qf);
    ffn_t_kernel<<<(M_ * FF_) / (256 * 8), 256, 0, stream>>>(qf, w1, b1, t_bf);
    gemm_mfma_kernel<0><<<dim3(E_ / 64, M_ / 128), 256, 0, stream>>>(t_bf, w2_bf, b2, ffn_out, E_, FF_);
    resid_ln_kernel<<<M_ / 4, 256, 0, stream>>>(h, ffn_out, g2, be2, out);
}